// Round 11
// baseline (749.845 us; speedup 1.0000x reference)
//
#include <hip/hip_runtime.h>
#include <hip/hip_bf16.h>

#define N_NODESC 100000
#define N_EDGESC 3200000
#define FDIM 512
#define MPAD 100096   // 391 * 256 = 782 * 128
#define NBLK 256      // chunks for bucket sort
#define EPB 12500     // edges per chunk (256*12500 = 3.2M exactly)
#define NBUCKB 391    // row buckets of 256 rows
#define NCNT (NBLK * NBUCKB)   // 100096
#define NB_SCAN ((NCNT + 8191) / 8192)   // 13

typedef __attribute__((ext_vector_type(4))) float f32x4;
typedef __attribute__((ext_vector_type(8))) __bf16 bf16x8;
typedef unsigned long long u64;

__device__ __forceinline__ void gload_lds16(const void* g, void* l) {
  __builtin_amdgcn_global_load_lds(
      (const __attribute__((address_space(1))) unsigned int*)g,
      (__attribute__((address_space(3))) unsigned int*)l, 16, 0, 0);
}

// ---- fused: bucket-count chunks (blocks 0..255) + wT convert (blocks 256..511) ----
__global__ __launch_bounds__(256) void k_bcount_wt(const int* __restrict__ rows,
                                                   int* __restrict__ cnt,
                                                   const float* __restrict__ w,
                                                   __bf16* __restrict__ wT) {
  __shared__ int h[NBUCKB];
  if (blockIdx.x >= NBLK) {
    const int b = blockIdx.x - NBLK;              // 0..255
    const int i0 = b * 1024 + threadIdx.x * 4;    // 4 elems/thread
    #pragma unroll
    for (int q = 0; q < 4; ++q) {
      const int j = i0 + q;
      const int k = j >> 9, n = j & (FDIM - 1);
      wT[n * FDIM + k] = (__bf16)w[j];
    }
    return;
  }
  const int blk = blockIdx.x;
  for (int i = threadIdx.x; i < NBUCKB; i += 256) h[i] = 0;
  __syncthreads();
  const int e0 = blk * EPB;
  for (int e = e0 + threadIdx.x; e < e0 + EPB; e += 256)
    atomicAdd(&h[rows[e] >> 8], 1);
  __syncthreads();
  for (int i = threadIdx.x; i < NBUCKB; i += 256) cnt[i * NBLK + blk] = h[i];
}

// ---- multi-block exclusive scan over cnt[0..NCNT): block-local pass ----
// bsum[b] keeps the RAW per-block total (consumers prefix it inline).
__global__ __launch_bounds__(1024) void k_scan1(int* __restrict__ d, int* __restrict__ bsum) {
  __shared__ int s[1024];
  const int t = threadIdx.x;
  const int base = blockIdx.x * 8192 + t * 8;
  int v[8];
  int sum = 0;
  #pragma unroll
  for (int k = 0; k < 8; ++k) {
    v[k] = (base + k < NCNT) ? d[base + k] : 0;
    sum += v[k];
  }
  s[t] = sum;
  __syncthreads();
  for (int dl = 1; dl < 1024; dl <<= 1) {
    int a = s[t];
    int b = (t >= dl) ? s[t - dl] : 0;
    __syncthreads();
    s[t] = a + b;
    __syncthreads();
  }
  int excl = (t == 0) ? 0 : s[t - 1];
  #pragma unroll
  for (int k = 0; k < 8; ++k) {
    if (base + k < NCNT) d[base + k] = excl;
    excl += v[k];
  }
  if (t == 1023) bsum[blockIdx.x] = s[1023];
}

// inline exclusive prefix of the 13 raw block sums -> E[] in LDS (wave 0)
__device__ __forceinline__ void prefix_bsum(const int* __restrict__ bsum, int* E) {
  if (threadIdx.x < 64) {
    const int t = threadIdx.x;
    int raw = (t < NB_SCAN) ? bsum[t] : 0;
    int v = raw;
    #pragma unroll
    for (int dl = 1; dl < 16; dl <<= 1) {
      const int u = __shfl_up(v, dl, 64);
      if (t >= dl) v += u;
    }
    if (t < NB_SCAN) E[t] = v - raw;
  }
}

// ---- bucket sort pass 2: scatter into (bucket,chunk) runs ----
// pack: val(32) | lrow(8) @bit17 | col(17)
__global__ __launch_bounds__(512) void k_bscatter(const int* __restrict__ rows,
                                                  const int* __restrict__ cols,
                                                  const float* __restrict__ vals,
                                                  const int* __restrict__ off,
                                                  const int* __restrict__ bsum,
                                                  u64* __restrict__ bedges) {
  __shared__ int E[16];
  __shared__ int lofs[NBUCKB];
  __shared__ int lcur[NBUCKB];
  const int blk = blockIdx.x;
  prefix_bsum(bsum, E);
  __syncthreads();
  for (int i = threadIdx.x; i < NBUCKB; i += 512) {
    const int idx = i * NBLK + blk;
    lofs[i] = off[idx] + E[idx >> 13];
    lcur[i] = 0;
  }
  __syncthreads();
  const int e0 = blk * EPB;
  for (int e = e0 + threadIdx.x; e < e0 + EPB; e += 512) {
    const int r = rows[e];
    const int b = r >> 8;
    const int p = lofs[b] + atomicAdd(&lcur[b], 1);
    bedges[p] = ((u64)__float_as_uint(vals[e]) << 32) |
                ((u64)(r & 255) << 17) | (unsigned)cols[e];
  }
}

// ---- CSR finalize: one block per bucket; LDS hist+scan; private-region scatter ----
__global__ __launch_bounds__(512) void k_csr(const int* __restrict__ off,
                                             const int* __restrict__ bsum,
                                             const u64* __restrict__ bedges,
                                             u64* __restrict__ edges,
                                             int* __restrict__ row_off) {
  __shared__ int E[16];
  __shared__ int hcnt[256];
  __shared__ int hcur[256];
  const int b = blockIdx.x;
  const int t = threadIdx.x;
  prefix_bsum(bsum, E);
  if (t < 256) hcnt[t] = 0;
  __syncthreads();
  const int i0 = b * NBLK;
  const int i1 = (b + 1) * NBLK;
  const int base  = off[i0] + E[i0 >> 13];
  const int nextb = (b + 1 < NBUCKB) ? (off[i1] + E[i1 >> 13]) : N_EDGESC;
  for (int j = base + t; j < nextb; j += 512)
    atomicAdd(&hcnt[(int)(bedges[j] >> 17) & 255], 1);
  __syncthreads();
  for (int d = 1; d < 256; d <<= 1) {
    int a = 0;
    if (t < 256) a = hcnt[t];
    int u = (t >= d && t < 256) ? hcnt[t - d] : 0;
    __syncthreads();
    if (t < 256) hcnt[t] = a + u;
    __syncthreads();
  }
  if (t < 256) {
    const int excl = (t == 0) ? 0 : hcnt[t - 1];
    row_off[b * 256 + t] = base + excl;
    hcur[t] = base + excl;
  }
  __syncthreads();
  for (int j = base + t; j < nextb; j += 512) {
    const u64 e = bedges[j];
    const int lr = (int)(e >> 17) & 255;
    const int p = atomicAdd(&hcur[lr], 1);
    edges[p] = (e & 0xFFFFFFFF00000000ull) | (e & 0x1FFFFull);
  }
}

// ---- GEMM: support[MPAD][512] (bf16) = x (f32, fused convert) @ w ----
// BM=128, BN=512 full width; A LDS-staged (f32->bf16), B read DIRECT from
// L2-resident wT (512KB) -- no lB, 16KB LDS total, barrier guards only A.
__global__ __launch_bounds__(512) void k_gemm(const float* __restrict__ x,
                                              const __bf16* __restrict__ wT,
                                              __bf16* __restrict__ support) {
  __shared__ __bf16 lA[2][128 * 32];   // 8KB each
  const int tm = blockIdx.x;
  const int tid = threadIdx.x;
  const int wid = tid >> 6;
  const int lane = tid & 63;
  const int wm = wid >> 2;      // 0..1
  const int wn = wid & 3;       // 0..3

  const long rowA0 = (long)tm * 128;

  // A staging geometry: thread covers row tid>>2, k-quarter (tid&3)*8 (8 f32)
  const int arow = tid >> 2;        // 0..127
  const int ah   = (tid & 3) * 8;   // 0,8,16,24

  f32x4 acc[4][8];
  #pragma unroll
  for (int m = 0; m < 4; ++m)
    #pragma unroll
    for (int n = 0; n < 8; ++n)
      acc[m][n] = (f32x4){0.f, 0.f, 0.f, 0.f};

  const long grow = rowA0 + arow;
  const long arowc = (grow < N_NODESC) ? grow : (N_NODESC - 1);
  const bool apad = grow >= N_NODESC;

  float4 ar[2];
  auto issueA = [&](int kt) {
    const int k0 = kt * 32;
    ar[0] = *(const float4*)(x + arowc * FDIM + k0 + ah);
    ar[1] = *(const float4*)(x + arowc * FDIM + k0 + ah + 4);
  };
  auto writeA = [&](int buf) {
    bf16x8 o;
    o[0] = (__bf16)(apad ? 0.f : ar[0].x);
    o[1] = (__bf16)(apad ? 0.f : ar[0].y);
    o[2] = (__bf16)(apad ? 0.f : ar[0].z);
    o[3] = (__bf16)(apad ? 0.f : ar[0].w);
    o[4] = (__bf16)(apad ? 0.f : ar[1].x);
    o[5] = (__bf16)(apad ? 0.f : ar[1].y);
    o[6] = (__bf16)(apad ? 0.f : ar[1].z);
    o[7] = (__bf16)(apad ? 0.f : ar[1].w);
    *(bf16x8*)&lA[buf][arow * 32 + ah] = o;
  };

  issueA(0);
  writeA(0);
  __syncthreads();

  const int frow = lane & 15;
  const int fk   = (lane >> 4) * 8;
  const __bf16* wbase = wT + (long)(wn * 128 + frow) * FDIM + fk;

  for (int kt = 0; kt < 16; ++kt) {
    const int buf = kt & 1;
    if (kt < 15) issueA(kt + 1);
    bf16x8 a[4], b[8];
    #pragma unroll
    for (int m = 0; m < 4; ++m)
      a[m] = *(const bf16x8*)&lA[buf][(wm * 64 + m * 16 + frow) * 32 + fk];
    #pragma unroll
    for (int n = 0; n < 8; ++n)
      b[n] = *(const bf16x8*)(wbase + (long)n * 16 * FDIM + kt * 32);
    #pragma unroll
    for (int m = 0; m < 4; ++m)
      #pragma unroll
      for (int n = 0; n < 8; ++n)
        acc[m][n] = __builtin_amdgcn_mfma_f32_16x16x32_bf16(a[m], b[n], acc[m][n], 0, 0, 0);
    if (kt < 15) writeA(buf ^ 1);
    __syncthreads();
  }

  // C/D layout (m89-verified): col = lane&15, row = (lane>>4)*4 + i
  const long crow0 = (long)tm * 128 + wm * 64 + (lane >> 4) * 4;
  const int  ccol0 = wn * 128 + frow;
  #pragma unroll
  for (int m = 0; m < 4; ++m)
    #pragma unroll
    for (int n = 0; n < 8; ++n)
      #pragma unroll
      for (int i = 0; i < 4; ++i)
        support[(crow0 + m * 16 + i) * (long)FDIM + ccol0 + n * 16] = (__bf16)acc[m][n][i];
}

// ---- SpMM (R3-proven): one wave per row, lane owns 8 features, f32 acc ----
__global__ __launch_bounds__(256) void k_spmm(const int* __restrict__ row_off,
                                              const u64* __restrict__ edges,
                                              const __bf16* __restrict__ support,
                                              float* __restrict__ out) {
  const int r = blockIdx.x * 4 + (threadIdx.x >> 6);
  const int lane = threadIdx.x & 63;
  if (r >= N_NODESC) return;
  const int beg = row_off[r];
  const int end = (r + 1 < N_NODESC) ? row_off[r + 1] : N_EDGESC;
  const __bf16* sp = support + lane * 8;

  float acc[8];
  #pragma unroll
  for (int i = 0; i < 8; ++i) acc[i] = 0.f;

  int j = beg;
  for (; j + 1 < end; j += 2) {
    const u64 e0 = edges[j];
    const u64 e1 = edges[j + 1];
    const bf16x8 s0 = *(const bf16x8*)(sp + (long)(unsigned)(e0 & 0xffffffffu) * FDIM);
    const bf16x8 s1 = *(const bf16x8*)(sp + (long)(unsigned)(e1 & 0xffffffffu) * FDIM);
    const float v0 = __uint_as_float((unsigned)(e0 >> 32));
    const float v1 = __uint_as_float((unsigned)(e1 >> 32));
    #pragma unroll
    for (int i = 0; i < 8; ++i) acc[i] += v0 * (float)s0[i];
    #pragma unroll
    for (int i = 0; i < 8; ++i) acc[i] += v1 * (float)s1[i];
  }
  if (j < end) {
    const u64 e0 = edges[j];
    const bf16x8 s0 = *(const bf16x8*)(sp + (long)(unsigned)(e0 & 0xffffffffu) * FDIM);
    const float v0 = __uint_as_float((unsigned)(e0 >> 32));
    #pragma unroll
    for (int i = 0; i < 8; ++i) acc[i] += v0 * (float)s0[i];
  }

  *(float4*)(out + (long)r * FDIM + lane * 8) =
      make_float4(acc[0], acc[1], acc[2], acc[3]);
  *(float4*)(out + (long)r * FDIM + lane * 8 + 4) =
      make_float4(acc[4], acc[5], acc[6], acc[7]);
}

extern "C" void kernel_launch(void* const* d_in, const int* in_sizes, int n_in,
                              void* d_out, int out_size, void* d_ws, size_t ws_size,
                              hipStream_t stream) {
  const float* x    = (const float*)d_in[0];
  const float* w    = (const float*)d_in[1];
  const int*   rows = (const int*)d_in[2];
  const int*   cols = (const int*)d_in[3];
  const float* vals = (const float*)d_in[4];
  float* out = (float*)d_out;

  char* ws = (char*)d_ws;
  size_t off = 0;
  auto alloc = [&](size_t bytes) {
    void* p = ws + off;
    off += (bytes + 255) & ~(size_t)255;
    return p;
  };
  __bf16* support = (__bf16*)alloc((size_t)MPAD * FDIM * 2);      // 102.5 MB
  __bf16* wT      = (__bf16*)alloc((size_t)FDIM * FDIM * 2);      // 0.5 MB
  int*    cnt     = (int*)alloc((size_t)(NCNT + 1) * 4);          // 0.4 MB
  int*    row_off = (int*)alloc((size_t)(MPAD + 1) * 4);          // 0.4 MB
  int*    bsum    = (int*)alloc(1024 * 4);
  u64*    edges   = (u64*)alloc((size_t)N_EDGESC * 8);            // 25.6 MB
  u64*    bedges  = (u64*)alloc((size_t)N_EDGESC * 8);            // 25.6 MB
  (void)ws_size;

  k_bcount_wt<<<NBLK + 256, 256, 0, stream>>>(rows, cnt, w, wT);
  k_scan1<<<NB_SCAN, 1024, 0, stream>>>(cnt, bsum);
  k_bscatter<<<NBLK, 512, 0, stream>>>(rows, cols, vals, cnt, bsum, bedges);
  k_csr<<<NBUCKB, 512, 0, stream>>>(cnt, bsum, bedges, edges, row_off);
  k_gemm<<<MPAD / 128, 512, 0, stream>>>(x, wT, support);
  k_spmm<<<N_NODESC / 4, 256, 0, stream>>>(row_off, edges, support, out);
}

// Round 12
// 697.816 us; speedup vs baseline: 1.0746x; 1.0746x over previous
//
#include <hip/hip_runtime.h>
#include <hip/hip_bf16.h>

#define N_NODESC 100000
#define N_EDGESC 3200000
#define FDIM 512
#define MPAD 100096   // 391 * 256 = 782 * 128
#define NBLK 256      // chunks for bucket sort
#define EPB 12500     // edges per chunk (256*12500 = 3.2M exactly)
#define NBUCKB 391    // row buckets of 256 rows
#define NCNT (NBLK * NBUCKB)   // 100096
#define NB_SCAN ((NCNT + 8191) / 8192)   // 13

typedef __attribute__((ext_vector_type(4))) float f32x4;
typedef __attribute__((ext_vector_type(8))) __bf16 bf16x8;
typedef unsigned long long u64;

__device__ __forceinline__ void gload_lds16(const void* g, void* l) {
  __builtin_amdgcn_global_load_lds(
      (const __attribute__((address_space(1))) unsigned int*)g,
      (__attribute__((address_space(3))) unsigned int*)l, 16, 0, 0);
}

// ---- fused: bucket-count chunks (blocks 0..255) + wT convert (blocks 256..511) ----
__global__ __launch_bounds__(256) void k_bcount_wt(const int* __restrict__ rows,
                                                   int* __restrict__ cnt,
                                                   const float* __restrict__ w,
                                                   __bf16* __restrict__ wT) {
  __shared__ int h[NBUCKB];
  if (blockIdx.x >= NBLK) {
    const int b = blockIdx.x - NBLK;              // 0..255
    const int i0 = b * 1024 + threadIdx.x * 4;    // 4 elems/thread
    #pragma unroll
    for (int q = 0; q < 4; ++q) {
      const int j = i0 + q;
      const int k = j >> 9, n = j & (FDIM - 1);
      wT[n * FDIM + k] = (__bf16)w[j];
    }
    return;
  }
  const int blk = blockIdx.x;
  for (int i = threadIdx.x; i < NBUCKB; i += 256) h[i] = 0;
  __syncthreads();
  const int e0 = blk * EPB;
  for (int e = e0 + threadIdx.x; e < e0 + EPB; e += 256)
    atomicAdd(&h[rows[e] >> 8], 1);
  __syncthreads();
  for (int i = threadIdx.x; i < NBUCKB; i += 256) cnt[i * NBLK + blk] = h[i];
}

// ---- multi-block exclusive scan over cnt[0..NCNT): block-local pass ----
// bsum[b] keeps the RAW per-block total (consumers prefix it inline).
__global__ __launch_bounds__(1024) void k_scan1(int* __restrict__ d, int* __restrict__ bsum) {
  __shared__ int s[1024];
  const int t = threadIdx.x;
  const int base = blockIdx.x * 8192 + t * 8;
  int v[8];
  int sum = 0;
  #pragma unroll
  for (int k = 0; k < 8; ++k) {
    v[k] = (base + k < NCNT) ? d[base + k] : 0;
    sum += v[k];
  }
  s[t] = sum;
  __syncthreads();
  for (int dl = 1; dl < 1024; dl <<= 1) {
    int a = s[t];
    int b = (t >= dl) ? s[t - dl] : 0;
    __syncthreads();
    s[t] = a + b;
    __syncthreads();
  }
  int excl = (t == 0) ? 0 : s[t - 1];
  #pragma unroll
  for (int k = 0; k < 8; ++k) {
    if (base + k < NCNT) d[base + k] = excl;
    excl += v[k];
  }
  if (t == 1023) bsum[blockIdx.x] = s[1023];
}

// inline exclusive prefix of the 13 raw block sums -> E[] in LDS (wave 0)
__device__ __forceinline__ void prefix_bsum(const int* __restrict__ bsum, int* E) {
  if (threadIdx.x < 64) {
    const int t = threadIdx.x;
    int raw = (t < NB_SCAN) ? bsum[t] : 0;
    int v = raw;
    #pragma unroll
    for (int dl = 1; dl < 16; dl <<= 1) {
      const int u = __shfl_up(v, dl, 64);
      if (t >= dl) v += u;
    }
    if (t < NB_SCAN) E[t] = v - raw;
  }
}

// ---- bucket sort pass 2: scatter into (bucket,chunk) runs ----
// pack: val(32) | lrow(8) @bit17 | col(17)
__global__ __launch_bounds__(512) void k_bscatter(const int* __restrict__ rows,
                                                  const int* __restrict__ cols,
                                                  const float* __restrict__ vals,
                                                  const int* __restrict__ off,
                                                  const int* __restrict__ bsum,
                                                  u64* __restrict__ bedges) {
  __shared__ int E[16];
  __shared__ int lofs[NBUCKB];
  __shared__ int lcur[NBUCKB];
  const int blk = blockIdx.x;
  prefix_bsum(bsum, E);
  __syncthreads();
  for (int i = threadIdx.x; i < NBUCKB; i += 512) {
    const int idx = i * NBLK + blk;
    lofs[i] = off[idx] + E[idx >> 13];
    lcur[i] = 0;
  }
  __syncthreads();
  const int e0 = blk * EPB;
  for (int e = e0 + threadIdx.x; e < e0 + EPB; e += 512) {
    const int r = rows[e];
    const int b = r >> 8;
    const int p = lofs[b] + atomicAdd(&lcur[b], 1);
    bedges[p] = ((u64)__float_as_uint(vals[e]) << 32) |
                ((u64)(r & 255) << 17) | (unsigned)cols[e];
  }
}

// ---- CSR finalize: one block per bucket; LDS hist+scan; private-region scatter ----
__global__ __launch_bounds__(512) void k_csr(const int* __restrict__ off,
                                             const int* __restrict__ bsum,
                                             const u64* __restrict__ bedges,
                                             u64* __restrict__ edges,
                                             int* __restrict__ row_off) {
  __shared__ int E[16];
  __shared__ int hcnt[256];
  __shared__ int hcur[256];
  const int b = blockIdx.x;
  const int t = threadIdx.x;
  prefix_bsum(bsum, E);
  if (t < 256) hcnt[t] = 0;
  __syncthreads();
  const int i0 = b * NBLK;
  const int i1 = (b + 1) * NBLK;
  const int base  = off[i0] + E[i0 >> 13];
  const int nextb = (b + 1 < NBUCKB) ? (off[i1] + E[i1 >> 13]) : N_EDGESC;
  for (int j = base + t; j < nextb; j += 512)
    atomicAdd(&hcnt[(int)(bedges[j] >> 17) & 255], 1);
  __syncthreads();
  for (int d = 1; d < 256; d <<= 1) {
    int a = 0;
    if (t < 256) a = hcnt[t];
    int u = (t >= d && t < 256) ? hcnt[t - d] : 0;
    __syncthreads();
    if (t < 256) hcnt[t] = a + u;
    __syncthreads();
  }
  if (t < 256) {
    const int excl = (t == 0) ? 0 : hcnt[t - 1];
    row_off[b * 256 + t] = base + excl;
    hcur[t] = base + excl;
  }
  __syncthreads();
  for (int j = base + t; j < nextb; j += 512) {
    const u64 e = bedges[j];
    const int lr = (int)(e >> 17) & 255;
    const int p = atomicAdd(&hcur[lr], 1);
    edges[p] = (e & 0xFFFFFFFF00000000ull) | (e & 0x1FFFFull);
  }
}

// ---- GEMM (R10-proven): support[MPAD][512] (bf16) = x (f32, fused convert) @ w ----
// BM=128, BN=512 (full width: x read ONCE), BK=32, 8 waves (2m x 4n)
__global__ __launch_bounds__(512) void k_gemm(const float* __restrict__ x,
                                              const __bf16* __restrict__ wT,
                                              __bf16* __restrict__ support) {
  __shared__ __bf16 lA[2][128 * 32];   // 8KB each
  __shared__ __bf16 lB[2][512 * 32];   // 32KB each, n-major: lB[n][k]
  const int tm = blockIdx.x;
  const int tid = threadIdx.x;
  const int wid = tid >> 6;
  const int lane = tid & 63;
  const int wm = wid >> 2;      // 0..1
  const int wn = wid & 3;       // 0..3

  const long rowA0 = (long)tm * 128;

  // B staging geometry (1KB chunks = 16 n-rows x 32 k)
  const int srow  = lane >> 2;
  const int skoff = (lane & 3) * 8;

  // A staging geometry: thread covers row tid>>2, k-quarter (tid&3)*8 (8 f32)
  const int arow = tid >> 2;        // 0..127
  const int ah   = (tid & 3) * 8;   // 0,8,16,24

  f32x4 acc[4][8];
  #pragma unroll
  for (int m = 0; m < 4; ++m)
    #pragma unroll
    for (int n = 0; n < 8; ++n)
      acc[m][n] = (f32x4){0.f, 0.f, 0.f, 0.f};

  const long grow = rowA0 + arow;
  const long arowc = (grow < N_NODESC) ? grow : (N_NODESC - 1);
  const bool apad = grow >= N_NODESC;

  float4 ar[2];
  auto issueA = [&](int kt) {
    const int k0 = kt * 32;
    ar[0] = *(const float4*)(x + arowc * FDIM + k0 + ah);
    ar[1] = *(const float4*)(x + arowc * FDIM + k0 + ah + 4);
  };
  auto writeA = [&](int buf) {
    bf16x8 o;
    o[0] = (__bf16)(apad ? 0.f : ar[0].x);
    o[1] = (__bf16)(apad ? 0.f : ar[0].y);
    o[2] = (__bf16)(apad ? 0.f : ar[0].z);
    o[3] = (__bf16)(apad ? 0.f : ar[0].w);
    o[4] = (__bf16)(apad ? 0.f : ar[1].x);
    o[5] = (__bf16)(apad ? 0.f : ar[1].y);
    o[6] = (__bf16)(apad ? 0.f : ar[1].z);
    o[7] = (__bf16)(apad ? 0.f : ar[1].w);
    *(bf16x8*)&lA[buf][arow * 32 + ah] = o;
  };
  auto stageB = [&](int buf, int kt) {
    const int k0 = kt * 32;
    #pragma unroll
    for (int it = 0; it < 4; ++it) {
      const int c = wid * 4 + it;   // chunk 0..31 (wave-uniform)
      const __bf16* gB = wT + (long)(c * 16 + srow) * FDIM + k0 + skoff;
      gload_lds16(gB, &lB[buf][c * 512]);
    }
  };

  issueA(0);
  stageB(0, 0);
  writeA(0);
  __syncthreads();

  const int frow = lane & 15;
  const int fk   = (lane >> 4) * 8;

  for (int kt = 0; kt < 16; ++kt) {
    const int buf = kt & 1;
    if (kt < 15) {
      issueA(kt + 1);
      stageB(buf ^ 1, kt + 1);
    }
    bf16x8 a[4], b[8];
    #pragma unroll
    for (int m = 0; m < 4; ++m)
      a[m] = *(const bf16x8*)&lA[buf][(wm * 64 + m * 16 + frow) * 32 + fk];
    #pragma unroll
    for (int n = 0; n < 8; ++n)
      b[n] = *(const bf16x8*)&lB[buf][(wn * 128 + n * 16 + frow) * 32 + fk];
    #pragma unroll
    for (int m = 0; m < 4; ++m)
      #pragma unroll
      for (int n = 0; n < 8; ++n)
        acc[m][n] = __builtin_amdgcn_mfma_f32_16x16x32_bf16(a[m], b[n], acc[m][n], 0, 0, 0);
    if (kt < 15) writeA(buf ^ 1);
    __syncthreads();
  }

  // C/D layout (m89-verified): col = lane&15, row = (lane>>4)*4 + i
  const long crow0 = (long)tm * 128 + wm * 64 + (lane >> 4) * 4;
  const int  ccol0 = wn * 128 + frow;
  #pragma unroll
  for (int m = 0; m < 4; ++m)
    #pragma unroll
    for (int n = 0; n < 8; ++n)
      #pragma unroll
      for (int i = 0; i < 4; ++i)
        support[(crow0 + m * 16 + i) * (long)FDIM + ccol0 + n * 16] = (__bf16)acc[m][n][i];
}

// ---- SpMM (R3-proven): one wave per row, lane owns 8 features, f32 acc ----
__global__ __launch_bounds__(256) void k_spmm(const int* __restrict__ row_off,
                                              const u64* __restrict__ edges,
                                              const __bf16* __restrict__ support,
                                              float* __restrict__ out) {
  const int r = blockIdx.x * 4 + (threadIdx.x >> 6);
  const int lane = threadIdx.x & 63;
  if (r >= N_NODESC) return;
  const int beg = row_off[r];
  const int end = (r + 1 < N_NODESC) ? row_off[r + 1] : N_EDGESC;
  const __bf16* sp = support + lane * 8;

  float acc[8];
  #pragma unroll
  for (int i = 0; i < 8; ++i) acc[i] = 0.f;

  int j = beg;
  for (; j + 1 < end; j += 2) {
    const u64 e0 = edges[j];
    const u64 e1 = edges[j + 1];
    const bf16x8 s0 = *(const bf16x8*)(sp + (long)(unsigned)(e0 & 0xffffffffu) * FDIM);
    const bf16x8 s1 = *(const bf16x8*)(sp + (long)(unsigned)(e1 & 0xffffffffu) * FDIM);
    const float v0 = __uint_as_float((unsigned)(e0 >> 32));
    const float v1 = __uint_as_float((unsigned)(e1 >> 32));
    #pragma unroll
    for (int i = 0; i < 8; ++i) acc[i] += v0 * (float)s0[i];
    #pragma unroll
    for (int i = 0; i < 8; ++i) acc[i] += v1 * (float)s1[i];
  }
  if (j < end) {
    const u64 e0 = edges[j];
    const bf16x8 s0 = *(const bf16x8*)(sp + (long)(unsigned)(e0 & 0xffffffffu) * FDIM);
    const float v0 = __uint_as_float((unsigned)(e0 >> 32));
    #pragma unroll
    for (int i = 0; i < 8; ++i) acc[i] += v0 * (float)s0[i];
  }

  *(float4*)(out + (long)r * FDIM + lane * 8) =
      make_float4(acc[0], acc[1], acc[2], acc[3]);
  *(float4*)(out + (long)r * FDIM + lane * 8 + 4) =
      make_float4(acc[4], acc[5], acc[6], acc[7]);
}

extern "C" void kernel_launch(void* const* d_in, const int* in_sizes, int n_in,
                              void* d_out, int out_size, void* d_ws, size_t ws_size,
                              hipStream_t stream) {
  const float* x    = (const float*)d_in[0];
  const float* w    = (const float*)d_in[1];
  const int*   rows = (const int*)d_in[2];
  const int*   cols = (const int*)d_in[3];
  const float* vals = (const float*)d_in[4];
  float* out = (float*)d_out;

  char* ws = (char*)d_ws;
  size_t off = 0;
  auto alloc = [&](size_t bytes) {
    void* p = ws + off;
    off += (bytes + 255) & ~(size_t)255;
    return p;
  };
  __bf16* support = (__bf16*)alloc((size_t)MPAD * FDIM * 2);      // 102.5 MB
  __bf16* wT      = (__bf16*)alloc((size_t)FDIM * FDIM * 2);      // 0.5 MB
  int*    cnt     = (int*)alloc((size_t)(NCNT + 1) * 4);          // 0.4 MB
  int*    row_off = (int*)alloc((size_t)(MPAD + 1) * 4);          // 0.4 MB
  int*    bsum    = (int*)alloc(1024 * 4);
  u64*    edges   = (u64*)alloc((size_t)N_EDGESC * 8);            // 25.6 MB
  u64*    bedges  = (u64*)alloc((size_t)N_EDGESC * 8);            // 25.6 MB
  (void)ws_size;

  k_bcount_wt<<<NBLK + 256, 256, 0, stream>>>(rows, cnt, w, wT);
  k_scan1<<<NB_SCAN, 1024, 0, stream>>>(cnt, bsum);
  k_bscatter<<<NBLK, 512, 0, stream>>>(rows, cols, vals, cnt, bsum, bedges);
  k_csr<<<NBUCKB, 512, 0, stream>>>(cnt, bsum, bedges, edges, row_off);
  k_gemm<<<MPAD / 128, 512, 0, stream>>>(x, wT, support);
  k_spmm<<<N_NODESC / 4, 256, 0, stream>>>(row_off, edges, support, out);
}